// Round 4
// baseline (1807.987 us; speedup 1.0000x reference)
//
#include <hip/hip_runtime.h>

#define NN 100000
#define RR 8
#define BB 8
#define DD 128
#define EE 800000
#define KT 1152                  // 128 (root) + 8*128 (relations)
#define NBLK 782                 // ceil(NN/128)
#define NSEG2 (NBLK * 1024)      // 800768 padded segment keys
#define ASTR 40                  // bf16 LDS row stride (80 B -> 2-way banks, free)
#define FSTR 132                 // Af transposed row stride in f32 (2-way banks)

typedef __attribute__((ext_vector_type(8))) __bf16 bf16x8;
typedef __attribute__((ext_vector_type(4))) float f32x4;
typedef __attribute__((ext_vector_type(4))) unsigned int u32x4;

__device__ __forceinline__ unsigned short f2bf(float f) {
    unsigned u = __float_as_uint(f);
    u += 0x7fffu + ((u >> 16) & 1u);          // round-to-nearest-even
    return (unsigned short)(u >> 16);
}
__device__ __forceinline__ float bf2f(unsigned short h) {
    return __uint_as_float(((unsigned)h) << 16);
}

// ---------------------------------------------------------------------------
// emb f32 -> bf16 (once; both layers then consume bf16 rows)
// ---------------------------------------------------------------------------
__global__ __launch_bounds__(256) void k_cvt(const float* __restrict__ x,
                                             unsigned short* __restrict__ xh) {
    int i = blockIdx.x * 256 + threadIdx.x;       // over NN*DD/8 = 1,600,000
    f32x4 a = ((const f32x4*)x)[2 * i];
    f32x4 b = ((const f32x4*)x)[2 * i + 1];
    u32x4 o;
    o[0] = (unsigned)f2bf(a[0]) | ((unsigned)f2bf(a[1]) << 16);
    o[1] = (unsigned)f2bf(a[2]) | ((unsigned)f2bf(a[3]) << 16);
    o[2] = (unsigned)f2bf(b[0]) | ((unsigned)f2bf(b[1]) << 16);
    o[3] = (unsigned)f2bf(b[2]) | ((unsigned)f2bf(b[3]) << 16);
    ((u32x4*)xh)[i] = o;
}

// ---------------------------------------------------------------------------
// Counting sort by key = (dst>>7)*1024 + rel*128 + (dst&127)
// ---------------------------------------------------------------------------
__global__ __launch_bounds__(256) void k_cnt(const int* __restrict__ ei,
                                             const int* __restrict__ et,
                                             int* __restrict__ cnt) {
    int e = blockIdx.x * 256 + threadIdx.x;
    if (e < EE) {
        int d = ei[EE + e];
        atomicAdd(&cnt[(d >> 7) * 1024 + et[e] * 128 + (d & 127)], 1);
    }
}

__global__ __launch_bounds__(256) void k_scan_local(const int* __restrict__ cnt,
                                                    int* __restrict__ loc,
                                                    int* __restrict__ bsum) {
    __shared__ int tmp[256];
    int t = threadIdx.x, i = blockIdx.x * 256 + t;
    int v = cnt[i];
    tmp[t] = v; __syncthreads();
    int val = v;
#pragma unroll
    for (int d = 1; d < 256; d <<= 1) {
        int a = (t >= d) ? tmp[t - d] : 0;
        __syncthreads();
        val += a; tmp[t] = val;
        __syncthreads();
    }
    loc[i] = val - v;
    if (t == 255) bsum[blockIdx.x] = val;
}

__global__ void k_scan_bsum(const int* __restrict__ bsum, int* __restrict__ boff) {
    __shared__ int tmp[256];
    const int NB = NSEG2 / 256;             // 3128
    const int CH = 13;                      // 256*13 >= 3128
    int t = threadIdx.x;
    int base = t * CH, s = 0;
    for (int j = 0; j < CH; ++j) { int idx = base + j; if (idx < NB) s += bsum[idx]; }
    tmp[t] = s; __syncthreads();
    int val = s;
#pragma unroll
    for (int d = 1; d < 256; d <<= 1) {
        int a = (t >= d) ? tmp[t - d] : 0;
        __syncthreads();
        val += a; tmp[t] = val;
        __syncthreads();
    }
    int run = val - s;
    for (int j = 0; j < CH; ++j) { int idx = base + j; if (idx < NB) { boff[idx] = run; run += bsum[idx]; } }
}

__global__ __launch_bounds__(256) void k_scan_add(int* __restrict__ loc,
                                                  const int* __restrict__ boff) {
    int i = blockIdx.x * 256 + threadIdx.x;
    loc[i] += boff[i >> 8];
}

// extract per-(block, rel) edge-range starts BEFORE scatter destroys segoff
__global__ __launch_bounds__(256) void k_roff(const int* __restrict__ segoff,
                                              int* __restrict__ roff) {
    int idx = blockIdx.x * 256 + threadIdx.x;
    if (idx < NBLK * 8) roff[idx] = segoff[(idx >> 3) * 1024 + (idx & 7) * 128];
    if (idx == NBLK * 8) roff[idx] = EE;
}

// scatter: pack src | dloc<<20; uses segoff as its cursor (destructive)
__global__ __launch_bounds__(256) void k_scatter(const int* __restrict__ ei,
                                                 const int* __restrict__ et,
                                                 int* __restrict__ segoff,
                                                 int* __restrict__ spk) {
    int e = blockIdx.x * 256 + threadIdx.x;
    if (e < EE) {
        int d = ei[EE + e];
        int key = (d >> 7) * 1024 + et[e] * 128 + (d & 127);
        int pos = atomicAdd(&segoff[key], 1);
        spk[pos] = ei[e] | ((d & 127) << 20);
    }
}

// ---------------------------------------------------------------------------
// B prep: BT[o][k] bf16 hi/lo; k<128 -> root, else W[r][i][o]
// ---------------------------------------------------------------------------
__global__ __launch_bounds__(256) void k_prepB(const float* __restrict__ root,
                                               const float* __restrict__ comp,
                                               const float* __restrict__ basis,
                                               unsigned short* __restrict__ Bhi,
                                               unsigned short* __restrict__ Blo) {
    int idx = blockIdx.x * 256 + threadIdx.x;   // DD*KT = 147456
    if (idx >= DD * KT) return;
    int o = idx / KT, k = idx - o * KT;
    float v;
    if (k < DD) {
        v = root[k * DD + o];
    } else {
        int r = (k - DD) >> 7, i = (k - DD) & 127;
        float s = 0.f;
#pragma unroll
        for (int b = 0; b < BB; ++b)
            s += comp[r * BB + b] * basis[((size_t)b * DD + i) * DD + o];
        v = s;
    }
    unsigned short hi = f2bf(v);
    Bhi[idx] = hi;
    Blo[idx] = f2bf(v - bf2f(hi));
}

// ---------------------------------------------------------------------------
// Fused agg + GEMM. Edge-parallel staging via native ds_add_f32
// (unsafeAtomicAdd — plain atomicAdd on LDS f32 expands to a CAS loop and
//  serializes the whole kernel; round-3 regression), 2 barriers/k-step.
// ---------------------------------------------------------------------------
template <bool WRITE_H1>
__global__ __launch_bounds__(256, 3) void k_gemm(
    const unsigned short* __restrict__ xh,
    const unsigned short* __restrict__ Bhi,
    const unsigned short* __restrict__ Blo,
    const float* __restrict__ bias,
    const int* __restrict__ spk,
    const int* __restrict__ roff,
    const int* __restrict__ cnt,
    unsigned short* __restrict__ h1h,
    float* __restrict__ outf)
{
    __shared__ unsigned short As[128 * ASTR];   // 10.2 KB
    __shared__ unsigned short Bhs[128 * ASTR];  // 10.2 KB
    __shared__ unsigned short Bls[128 * ASTR];  // 10.2 KB
    __shared__ float Af[32 * FSTR];             // 16.9 KB, transposed [c][dl]
    __shared__ float sinv[1024];                // 4 KB
    __shared__ int reb[9];

    const int tid = threadIdx.x;
    const int b = blockIdx.x;
    const int M0 = b * 128;

    if (tid < 9) reb[tid] = roff[b * 8 + tid];
#pragma unroll
    for (int p = 0; p < 4; ++p) {
        int i = p * 256 + tid;
        int c = cnt[b * 1024 + i];
        sinv[i] = 1.0f / (float)(c > 1 ? c : 1);
    }
    for (int i = tid; i < 32 * FSTR / 4; i += 256)
        ((f32x4*)Af)[i] = (f32x4){0.f, 0.f, 0.f, 0.f};

    const int wave = tid >> 6, lane = tid & 63;
    const int quad = lane >> 4, lm = lane & 15;
    const int erow = tid >> 1, half = tid & 1;

    float bv[8];
#pragma unroll
    for (int nt = 0; nt < 8; ++nt) bv[nt] = bias[nt * 16 + lm];

    f32x4 acc[2][8];
#pragma unroll
    for (int a = 0; a < 2; ++a)
#pragma unroll
        for (int n = 0; n < 8; ++n) acc[a][n] = (f32x4){0.f, 0.f, 0.f, 0.f};

    __syncthreads();

    for (int ks = 0; ks < KT / 32; ++ks) {
        const int k0 = ks * 32;
        if (ks >= 4) {
            // ---- edge-parallel gather into Af (overlaps prior MFMA)
            const int r = (ks - 4) >> 2;
            const int i0 = ((ks - 4) & 3) * 32;
            const int ee = reb[r + 1];
            for (int e = reb[r] + erow; e < ee; e += 128) {
                int pk = spk[e];
                int s = pk & 0xFFFFF;
                int dl = pk >> 20;
                const u32x4* px = (const u32x4*)(xh + (size_t)s * DD + i0 + half * 16);
                u32x4 w0 = px[0];
                u32x4 w1 = px[1];
                const int cb = half * 16;
#pragma unroll
                for (int j = 0; j < 4; ++j) {
                    unsigned u = w0[j];
                    unsafeAtomicAdd(&Af[(cb + 2 * j) * FSTR + dl],     __uint_as_float(u << 16));
                    unsafeAtomicAdd(&Af[(cb + 2 * j + 1) * FSTR + dl], __uint_as_float(u & 0xFFFF0000u));
                }
#pragma unroll
                for (int j = 0; j < 4; ++j) {
                    unsigned u = w1[j];
                    unsafeAtomicAdd(&Af[(cb + 8 + 2 * j) * FSTR + dl],     __uint_as_float(u << 16));
                    unsafeAtomicAdd(&Af[(cb + 8 + 2 * j + 1) * FSTR + dl], __uint_as_float(u & 0xFFFF0000u));
                }
            }
        }
        __syncthreads();                         // gather done

        // ---- As staging
        if (ks < 4) {                            // root block: straight bf16 copy
            int nidx = M0 + erow; if (nidx > NN - 1) nidx = NN - 1;
            const u32x4* px = (const u32x4*)(xh + (size_t)nidx * DD + k0 + half * 16);
            u32x4 a0 = px[0], a1 = px[1];
            unsigned short* pa = &As[erow * ASTR + half * 16];
            *(u32x4*)pa = a0;
            *(u32x4*)(pa + 8) = a1;
        } else {                                 // scale by inv count, pack, re-zero Af
            const int r = (ks - 4) >> 2;
            const float sc = sinv[r * 128 + erow];
            const int cb = half * 16;
            unsigned pk8[8];
#pragma unroll
            for (int j = 0; j < 8; ++j) {
                float v0 = Af[(cb + 2 * j) * FSTR + erow];
                float v1 = Af[(cb + 2 * j + 1) * FSTR + erow];
                Af[(cb + 2 * j) * FSTR + erow] = 0.f;
                Af[(cb + 2 * j + 1) * FSTR + erow] = 0.f;
                pk8[j] = (unsigned)f2bf(v0 * sc) | ((unsigned)f2bf(v1 * sc) << 16);
            }
            unsigned short* pa = &As[erow * ASTR + half * 16];
            *(u32x4*)pa = (u32x4){pk8[0], pk8[1], pk8[2], pk8[3]};
            *(u32x4*)(pa + 8) = (u32x4){pk8[4], pk8[5], pk8[6], pk8[7]};
        }
        // ---- B staging
#pragma unroll
        for (int p = 0; p < 2; ++p) {
            int c2 = p * 256 + tid;
            int o = c2 >> 2, q = c2 & 3;
            int goff = o * KT + k0 + q * 8;
            *(u32x4*)&Bhs[o * ASTR + q * 8] = *(const u32x4*)(Bhi + goff);
            *(u32x4*)&Bls[o * ASTR + q * 8] = *(const u32x4*)(Blo + goff);
        }
        __syncthreads();                         // tiles ready

        // ---- MFMA: 2 m-tiles x 8 n-tiles, B hi+lo compensated
        bf16x8 af0 = __builtin_bit_cast(bf16x8, *(const u32x4*)&As[(wave * 32 + lm) * ASTR + quad * 8]);
        bf16x8 af1 = __builtin_bit_cast(bf16x8, *(const u32x4*)&As[(wave * 32 + 16 + lm) * ASTR + quad * 8]);
#pragma unroll
        for (int nt = 0; nt < 8; ++nt) {
            bf16x8 bh = __builtin_bit_cast(bf16x8, *(const u32x4*)&Bhs[(nt * 16 + lm) * ASTR + quad * 8]);
            bf16x8 bl = __builtin_bit_cast(bf16x8, *(const u32x4*)&Bls[(nt * 16 + lm) * ASTR + quad * 8]);
            acc[0][nt] = __builtin_amdgcn_mfma_f32_16x16x32_bf16(af0, bh, acc[0][nt], 0, 0, 0);
            acc[0][nt] = __builtin_amdgcn_mfma_f32_16x16x32_bf16(af0, bl, acc[0][nt], 0, 0, 0);
            acc[1][nt] = __builtin_amdgcn_mfma_f32_16x16x32_bf16(af1, bh, acc[1][nt], 0, 0, 0);
            acc[1][nt] = __builtin_amdgcn_mfma_f32_16x16x32_bf16(af1, bl, acc[1][nt], 0, 0, 0);
        }
        // no trailing barrier: next writes to As/B are after the next gather barrier
    }

    // ---- epilogue (C/D: col=lane&15, row=quad*4+reg)
#pragma unroll
    for (int mt = 0; mt < 2; ++mt) {
#pragma unroll
        for (int nt = 0; nt < 8; ++nt) {
#pragma unroll
            for (int rg = 0; rg < 4; ++rg) {
                int row = M0 + wave * 32 + mt * 16 + quad * 4 + rg;
                if (row < NN) {
                    int col = nt * 16 + lm;
                    float v = acc[mt][nt][rg] + bv[nt];
                    if (WRITE_H1) h1h[(size_t)row * DD + col] = f2bf(fmaxf(v, 0.f));
                    else          outf[(size_t)row * DD + col] = v;
                }
            }
        }
    }
}

// ---------------------------------------------------------------------------

extern "C" void kernel_launch(void* const* d_in, const int* in_sizes, int n_in,
                              void* d_out, int out_size, void* d_ws, size_t ws_size,
                              hipStream_t stream) {
    const int*   ei     = (const int*)d_in[0];
    const int*   et     = (const int*)d_in[1];
    const float* emb    = (const float*)d_in[2];
    const float* basis1 = (const float*)d_in[3];
    const float* comp1  = (const float*)d_in[4];
    const float* root1  = (const float*)d_in[5];
    const float* bias1  = (const float*)d_in[6];
    const float* basis2 = (const float*)d_in[7];
    const float* comp2  = (const float*)d_in[8];
    const float* root2  = (const float*)d_in[9];
    const float* bias2  = (const float*)d_in[10];
    float* out = (float*)d_out;
    (void)in_sizes; (void)n_in; (void)out_size; (void)ws_size;

    char* ws = (char*)d_ws;
    int*            cnt    = (int*)(ws + 0);           // 3,203,072 B
    int*            segoff = (int*)(ws + 3203072);     // 3,203,072 B
    int*            spk    = (int*)(ws + 6406144);     // 3,200,000 B
    int*            bsum   = (int*)(ws + 9606144);     // 12,512 B
    int*            boff   = (int*)(ws + 9618656);     // 12,512 B
    int*            roffp  = (int*)(ws + 9631168);     // 25,028 B (pad to 9,656,320)
    unsigned short* Bhi1   = (unsigned short*)(ws + 9656320);    // 294,912 B each
    unsigned short* Blo1   = (unsigned short*)(ws + 9951232);
    unsigned short* Bhi2   = (unsigned short*)(ws + 10246144);
    unsigned short* Blo2   = (unsigned short*)(ws + 10541056);
    unsigned short* embh   = (unsigned short*)(ws + 10835968);   // 25.6 MB
    unsigned short* h1h    = (unsigned short*)(ws + 36435968);   // 25.6 MB -> end 62.0 MB

    hipMemsetAsync(cnt, 0, (size_t)NSEG2 * 4, stream);

    k_cvt       <<<NN * DD / (256 * 8), 256, 0, stream>>>(emb, embh);
    k_cnt       <<<(EE + 255) / 256, 256, 0, stream>>>(ei, et, cnt);
    k_scan_local<<<NSEG2 / 256, 256, 0, stream>>>(cnt, segoff, bsum);
    k_scan_bsum <<<1, 256, 0, stream>>>(bsum, boff);
    k_scan_add  <<<NSEG2 / 256, 256, 0, stream>>>(segoff, boff);
    k_roff      <<<(NBLK * 8 + 256) / 256, 256, 0, stream>>>(segoff, roffp);
    k_scatter   <<<(EE + 255) / 256, 256, 0, stream>>>(ei, et, segoff, spk);

    k_prepB<<<(DD * KT + 255) / 256, 256, 0, stream>>>(root1, comp1, basis1, Bhi1, Blo1);
    k_prepB<<<(DD * KT + 255) / 256, 256, 0, stream>>>(root2, comp2, basis2, Bhi2, Blo2);

    k_gemm<true> <<<NBLK, 256, 0, stream>>>(embh, Bhi1, Blo1, bias1, spk, roffp, cnt, h1h, nullptr);
    k_gemm<false><<<NBLK, 256, 0, stream>>>(h1h,  Bhi2, Blo2, bias2, spk, roffp, cnt, nullptr, out);
}

// Round 5
// 564.750 us; speedup vs baseline: 3.2014x; 3.2014x over previous
//
#include <hip/hip_runtime.h>

#define NN 100000
#define RR 8
#define BB 8
#define DD 128
#define EE 800000
#define KT 1152                  // 128 (root) + 8*128 (relations)
#define NBLK 782                 // ceil(NN/128)
#define NSEG2 (NBLK * 1024)      // 800768 padded segment keys
#define ASTR 40                  // bf16 LDS row stride for As/B (80 B)
#define AESTR 40                 // bf16 LDS row stride for Ae (80 B, 16B-aligned rows)
#define ECH 192                  // edge-chunk size (Poisson(128) -> ~always 1 chunk)

typedef __attribute__((ext_vector_type(8))) __bf16 bf16x8;
typedef __attribute__((ext_vector_type(4))) float f32x4;
typedef __attribute__((ext_vector_type(4))) unsigned int u32x4;

__device__ __forceinline__ unsigned short f2bf(float f) {
    unsigned u = __float_as_uint(f);
    u += 0x7fffu + ((u >> 16) & 1u);          // round-to-nearest-even
    return (unsigned short)(u >> 16);
}
__device__ __forceinline__ float bf2f(unsigned short h) {
    return __uint_as_float(((unsigned)h) << 16);
}

// ---------------------------------------------------------------------------
// emb f32 -> bf16 (once; both layers then consume bf16 rows)
// ---------------------------------------------------------------------------
__global__ __launch_bounds__(256) void k_cvt(const float* __restrict__ x,
                                             unsigned short* __restrict__ xh) {
    int i = blockIdx.x * 256 + threadIdx.x;       // over NN*DD/8 = 1,600,000
    f32x4 a = ((const f32x4*)x)[2 * i];
    f32x4 b = ((const f32x4*)x)[2 * i + 1];
    u32x4 o;
    o[0] = (unsigned)f2bf(a[0]) | ((unsigned)f2bf(a[1]) << 16);
    o[1] = (unsigned)f2bf(a[2]) | ((unsigned)f2bf(a[3]) << 16);
    o[2] = (unsigned)f2bf(b[0]) | ((unsigned)f2bf(b[1]) << 16);
    o[3] = (unsigned)f2bf(b[2]) | ((unsigned)f2bf(b[3]) << 16);
    ((u32x4*)xh)[i] = o;
}

// ---------------------------------------------------------------------------
// Counting sort by key = (dst>>7)*1024 + rel*128 + (dst&127)
// ---------------------------------------------------------------------------
__global__ __launch_bounds__(256) void k_cnt(const int* __restrict__ ei,
                                             const int* __restrict__ et,
                                             int* __restrict__ cnt) {
    int e = blockIdx.x * 256 + threadIdx.x;
    if (e < EE) {
        int d = ei[EE + e];
        atomicAdd(&cnt[(d >> 7) * 1024 + et[e] * 128 + (d & 127)], 1);
    }
}

__global__ __launch_bounds__(256) void k_scan_local(const int* __restrict__ cnt,
                                                    int* __restrict__ loc,
                                                    int* __restrict__ bsum) {
    __shared__ int tmp[256];
    int t = threadIdx.x, i = blockIdx.x * 256 + t;
    int v = cnt[i];
    tmp[t] = v; __syncthreads();
    int val = v;
#pragma unroll
    for (int d = 1; d < 256; d <<= 1) {
        int a = (t >= d) ? tmp[t - d] : 0;
        __syncthreads();
        val += a; tmp[t] = val;
        __syncthreads();
    }
    loc[i] = val - v;
    if (t == 255) bsum[blockIdx.x] = val;
}

__global__ void k_scan_bsum(const int* __restrict__ bsum, int* __restrict__ boff) {
    __shared__ int tmp[256];
    const int NB = NSEG2 / 256;             // 3128
    const int CH = 13;                      // 256*13 >= 3128
    int t = threadIdx.x;
    int base = t * CH, s = 0;
    for (int j = 0; j < CH; ++j) { int idx = base + j; if (idx < NB) s += bsum[idx]; }
    tmp[t] = s; __syncthreads();
    int val = s;
#pragma unroll
    for (int d = 1; d < 256; d <<= 1) {
        int a = (t >= d) ? tmp[t - d] : 0;
        __syncthreads();
        val += a; tmp[t] = val;
        __syncthreads();
    }
    int run = val - s;
    for (int j = 0; j < CH; ++j) { int idx = base + j; if (idx < NB) { boff[idx] = run; run += bsum[idx]; } }
}

__global__ __launch_bounds__(256) void k_scan_add(int* __restrict__ loc,
                                                  const int* __restrict__ boff) {
    int i = blockIdx.x * 256 + threadIdx.x;
    loc[i] += boff[i >> 8];
}

// extract per-(block, rel) edge-range starts BEFORE scatter destroys segoff
__global__ __launch_bounds__(256) void k_roff(const int* __restrict__ segoff,
                                              int* __restrict__ roff) {
    int idx = blockIdx.x * 256 + threadIdx.x;
    if (idx < NBLK * 8) roff[idx] = segoff[(idx >> 3) * 1024 + (idx & 7) * 128];
    if (idx == NBLK * 8) roff[idx] = EE;
}

// scatter: pack src; uses segoff as its cursor (post-scatter segoff = segment END,
// so k_gemm recovers beg = segoff[key] - cnt[key])
__global__ __launch_bounds__(256) void k_scatter(const int* __restrict__ ei,
                                                 const int* __restrict__ et,
                                                 int* __restrict__ segoff,
                                                 int* __restrict__ spk) {
    int e = blockIdx.x * 256 + threadIdx.x;
    if (e < EE) {
        int d = ei[EE + e];
        int key = (d >> 7) * 1024 + et[e] * 128 + (d & 127);
        int pos = atomicAdd(&segoff[key], 1);
        spk[pos] = ei[e];
    }
}

// ---------------------------------------------------------------------------
// B prep: BT[o][k] bf16 hi/lo; k<128 -> root, else W[r][i][o]
// ---------------------------------------------------------------------------
__global__ __launch_bounds__(256) void k_prepB(const float* __restrict__ root,
                                               const float* __restrict__ comp,
                                               const float* __restrict__ basis,
                                               unsigned short* __restrict__ Bhi,
                                               unsigned short* __restrict__ Blo) {
    int idx = blockIdx.x * 256 + threadIdx.x;   // DD*KT = 147456
    if (idx >= DD * KT) return;
    int o = idx / KT, k = idx - o * KT;
    float v;
    if (k < DD) {
        v = root[k * DD + o];
    } else {
        int r = (k - DD) >> 7, i = (k - DD) & 127;
        float s = 0.f;
#pragma unroll
        for (int b = 0; b < BB; ++b)
            s += comp[r * BB + b] * basis[((size_t)b * DD + i) * DD + o];
        v = s;
    }
    unsigned short hi = f2bf(v);
    Bhi[idx] = hi;
    Blo[idx] = f2bf(v - bf2f(hi));
}

// ---------------------------------------------------------------------------
// Fused agg + GEMM. Stage-then-owner-reduce (NO fp LDS atomics — rounds 3/4
// showed fp LDS atomicAdd/unsafeAtomicAdd both serialize catastrophically).
// Per k-step (relation r, col slice i0): stage <=192 edges' 64B slices into
// Ae (1 thread = 1 edge, parallel), barrier, then each (node,half) owner sums
// its segment's slots from LDS. ~3 barriers/k-step.
// ---------------------------------------------------------------------------
template <bool WRITE_H1>
__global__ __launch_bounds__(256, 3) void k_gemm(
    const unsigned short* __restrict__ xh,
    const unsigned short* __restrict__ Bhi,
    const unsigned short* __restrict__ Blo,
    const float* __restrict__ bias,
    const int* __restrict__ spk,
    const int* __restrict__ roff,
    const int* __restrict__ segend,     // post-scatter segoff = segment ends
    const int* __restrict__ cnt,
    unsigned short* __restrict__ h1h,
    float* __restrict__ outf)
{
    __shared__ unsigned short As[128 * ASTR];    // 10.2 KB
    __shared__ unsigned short Bhs[128 * ASTR];   // 10.2 KB
    __shared__ unsigned short Bls[128 * ASTR];   // 10.2 KB
    __shared__ unsigned short Ae[ECH * AESTR];   // 15.4 KB edge-staging tile
    __shared__ int sbeg[1024];                   // 4 KB
    __shared__ unsigned short scnt[1024];        // 2 KB
    __shared__ int reb[9];

    const int tid = threadIdx.x;
    const int b = blockIdx.x;
    const int M0 = b * 128;

    if (tid < 9) reb[tid] = roff[b * 8 + tid];
#pragma unroll
    for (int p = 0; p < 4; ++p) {
        int i = p * 256 + tid;
        int end = segend[b * 1024 + i];
        int c = cnt[b * 1024 + i];
        sbeg[i] = end - c;
        scnt[i] = (unsigned short)c;
    }

    const int wave = tid >> 6, lane = tid & 63;
    const int quad = lane >> 4, lm = lane & 15;
    const int erow = tid >> 1, half = tid & 1;

    float bv[8];
#pragma unroll
    for (int nt = 0; nt < 8; ++nt) bv[nt] = bias[nt * 16 + lm];

    f32x4 acc[2][8];
#pragma unroll
    for (int a = 0; a < 2; ++a)
#pragma unroll
        for (int n = 0; n < 8; ++n) acc[a][n] = (f32x4){0.f, 0.f, 0.f, 0.f};

    __syncthreads();

    for (int ks = 0; ks < KT / 32; ++ks) {
        const int k0 = ks * 32;

        if (ks < 4) {
            // root block: As = xh rows (straight bf16 copy)
            int nidx = M0 + erow; if (nidx > NN - 1) nidx = NN - 1;
            const u32x4* px = (const u32x4*)(xh + (size_t)nidx * DD + k0 + half * 16);
            u32x4 a0 = px[0], a1 = px[1];
            __syncthreads();                     // prev MFMA readers of As/B done
            unsigned short* pa = &As[erow * ASTR + half * 16];
            *(u32x4*)pa = a0;
            *(u32x4*)(pa + 8) = a1;
        } else {
            const int r = (ks - 4) >> 2;
            const int i0 = ((ks - 4) & 3) * 32;
            const int rb = reb[r], rend = reb[r + 1];
            const int si = r * 128 + erow;
            const int beg = sbeg[si];
            const int cs = scnt[si];
            const int send_ = beg + cs;

            float v[16];
#pragma unroll
            for (int j = 0; j < 16; ++j) v[j] = 0.f;

            if (rb >= rend) __syncthreads();     // keep As-write hazard barrier
            for (int cb0 = rb; cb0 < rend; cb0 += ECH) {
                // ---- stage: 1 thread = 1 edge, 64 B slice of its source row
                u32x4 a0 = {}, a1 = {}, a2 = {}, a3 = {};
                const int e = cb0 + tid;
                const bool have = (tid < ECH) && (e < rend);
                if (have) {
                    const int s = spk[e];
                    const u32x4* px = (const u32x4*)(xh + (size_t)s * DD + i0);
                    a0 = px[0]; a1 = px[1]; a2 = px[2]; a3 = px[3];
                }
                __syncthreads();                 // prev readers of Ae (and As) done
                if (have) {
                    u32x4* pe = (u32x4*)&Ae[tid * AESTR];
                    pe[0] = a0; pe[1] = a1; pe[2] = a2; pe[3] = a3;
                }
                __syncthreads();                 // stage visible
                // ---- owner reduce: (node erow, half) sums its segment's slots
                int lo = beg > cb0 ? beg : cb0;
                int hi2 = send_ < cb0 + ECH ? send_ : cb0 + ECH;
                for (int e2 = lo; e2 < hi2; ++e2) {
                    const unsigned* pe = (const unsigned*)&Ae[(e2 - cb0) * AESTR + half * 16];
#pragma unroll
                    for (int q = 0; q < 8; ++q) {
                        unsigned u = pe[q];
                        v[2 * q]     += __uint_as_float(u << 16);
                        v[2 * q + 1] += __uint_as_float(u & 0xFFFF0000u);
                    }
                }
            }
            // ---- pack mean into As
            const float inv = 1.0f / (float)(cs > 1 ? cs : 1);
            unsigned pk8[8];
#pragma unroll
            for (int j = 0; j < 8; ++j)
                pk8[j] = (unsigned)f2bf(v[2 * j] * inv) | ((unsigned)f2bf(v[2 * j + 1] * inv) << 16);
            unsigned short* pa = &As[erow * ASTR + half * 16];
            *(u32x4*)pa = (u32x4){pk8[0], pk8[1], pk8[2], pk8[3]};
            *(u32x4*)(pa + 8) = (u32x4){pk8[4], pk8[5], pk8[6], pk8[7]};
        }

        // ---- B staging
#pragma unroll
        for (int p = 0; p < 2; ++p) {
            int c2 = p * 256 + tid;
            int o = c2 >> 2, q = c2 & 3;
            int goff = o * KT + k0 + q * 8;
            *(u32x4*)&Bhs[o * ASTR + q * 8] = *(const u32x4*)(Bhi + goff);
            *(u32x4*)&Bls[o * ASTR + q * 8] = *(const u32x4*)(Blo + goff);
        }
        __syncthreads();                         // tiles ready

        // ---- MFMA: 2 m-tiles x 8 n-tiles, B hi+lo compensated
        bf16x8 af0 = __builtin_bit_cast(bf16x8, *(const u32x4*)&As[(wave * 32 + lm) * ASTR + quad * 8]);
        bf16x8 af1 = __builtin_bit_cast(bf16x8, *(const u32x4*)&As[(wave * 32 + 16 + lm) * ASTR + quad * 8]);
#pragma unroll
        for (int nt = 0; nt < 8; ++nt) {
            bf16x8 bh = __builtin_bit_cast(bf16x8, *(const u32x4*)&Bhs[(nt * 16 + lm) * ASTR + quad * 8]);
            bf16x8 bl = __builtin_bit_cast(bf16x8, *(const u32x4*)&Bls[(nt * 16 + lm) * ASTR + quad * 8]);
            acc[0][nt] = __builtin_amdgcn_mfma_f32_16x16x32_bf16(af0, bh, acc[0][nt], 0, 0, 0);
            acc[0][nt] = __builtin_amdgcn_mfma_f32_16x16x32_bf16(af0, bl, acc[0][nt], 0, 0, 0);
            acc[1][nt] = __builtin_amdgcn_mfma_f32_16x16x32_bf16(af1, bh, acc[1][nt], 0, 0, 0);
            acc[1][nt] = __builtin_amdgcn_mfma_f32_16x16x32_bf16(af1, bl, acc[1][nt], 0, 0, 0);
        }
        // no trailing barrier: next k-step's LDS writes are behind its own barriers
    }

    // ---- epilogue (C/D: col=lane&15, row=quad*4+reg)
#pragma unroll
    for (int mt = 0; mt < 2; ++mt) {
#pragma unroll
        for (int nt = 0; nt < 8; ++nt) {
#pragma unroll
            for (int rg = 0; rg < 4; ++rg) {
                int row = M0 + wave * 32 + mt * 16 + quad * 4 + rg;
                if (row < NN) {
                    int col = nt * 16 + lm;
                    float v = acc[mt][nt][rg] + bv[nt];
                    if (WRITE_H1) h1h[(size_t)row * DD + col] = f2bf(fmaxf(v, 0.f));
                    else          outf[(size_t)row * DD + col] = v;
                }
            }
        }
    }
}

// ---------------------------------------------------------------------------

extern "C" void kernel_launch(void* const* d_in, const int* in_sizes, int n_in,
                              void* d_out, int out_size, void* d_ws, size_t ws_size,
                              hipStream_t stream) {
    const int*   ei     = (const int*)d_in[0];
    const int*   et     = (const int*)d_in[1];
    const float* emb    = (const float*)d_in[2];
    const float* basis1 = (const float*)d_in[3];
    const float* comp1  = (const float*)d_in[4];
    const float* root1  = (const float*)d_in[5];
    const float* bias1  = (const float*)d_in[6];
    const float* basis2 = (const float*)d_in[7];
    const float* comp2  = (const float*)d_in[8];
    const float* root2  = (const float*)d_in[9];
    const float* bias2  = (const float*)d_in[10];
    float* out = (float*)d_out;
    (void)in_sizes; (void)n_in; (void)out_size; (void)ws_size;

    char* ws = (char*)d_ws;
    int*            cnt    = (int*)(ws + 0);           // 3,203,072 B
    int*            segoff = (int*)(ws + 3203072);     // 3,203,072 B (post-scatter = ends)
    int*            spk    = (int*)(ws + 6406144);     // 3,200,000 B
    int*            bsum   = (int*)(ws + 9606144);     // 12,512 B
    int*            boff   = (int*)(ws + 9618656);     // 12,512 B
    int*            roffp  = (int*)(ws + 9631168);     // 25,028 B (pad to 9,656,320)
    unsigned short* Bhi1   = (unsigned short*)(ws + 9656320);    // 294,912 B each
    unsigned short* Blo1   = (unsigned short*)(ws + 9951232);
    unsigned short* Bhi2   = (unsigned short*)(ws + 10246144);
    unsigned short* Blo2   = (unsigned short*)(ws + 10541056);
    unsigned short* embh   = (unsigned short*)(ws + 10835968);   // 25.6 MB
    unsigned short* h1h    = (unsigned short*)(ws + 36435968);   // 25.6 MB -> end 62.0 MB

    hipMemsetAsync(cnt, 0, (size_t)NSEG2 * 4, stream);

    k_cvt       <<<NN * DD / (256 * 8), 256, 0, stream>>>(emb, embh);
    k_cnt       <<<(EE + 255) / 256, 256, 0, stream>>>(ei, et, cnt);
    k_scan_local<<<NSEG2 / 256, 256, 0, stream>>>(cnt, segoff, bsum);
    k_scan_bsum <<<1, 256, 0, stream>>>(bsum, boff);
    k_scan_add  <<<NSEG2 / 256, 256, 0, stream>>>(segoff, boff);
    k_roff      <<<(NBLK * 8 + 256) / 256, 256, 0, stream>>>(segoff, roffp);
    k_scatter   <<<(EE + 255) / 256, 256, 0, stream>>>(ei, et, segoff, spk);

    k_prepB<<<(DD * KT + 255) / 256, 256, 0, stream>>>(root1, comp1, basis1, Bhi1, Blo1);
    k_prepB<<<(DD * KT + 255) / 256, 256, 0, stream>>>(root2, comp2, basis2, Bhi2, Blo2);

    k_gemm<true> <<<NBLK, 256, 0, stream>>>(embh, Bhi1, Blo1, bias1, spk, roffp, segoff, cnt, h1h, nullptr);
    k_gemm<false><<<NBLK, 256, 0, stream>>>(h1h,  Bhi2, Blo2, bias2, spk, roffp, segoff, cnt, nullptr, out);
}